// Round 1
// baseline (463.904 us; speedup 1.0000x reference)
//
#include <hip/hip_runtime.h>

#define NIN  20
#define NHID 6
#define NOUT 6

__device__ __forceinline__ float fsig(float t) {
    // sigmoid(t) = 1/(1+exp(-t)); v_exp_f32 + v_rcp_f32, ~1e-7 rel error
    return __builtin_amdgcn_rcpf(1.0f + __expf(-t));
}

__global__ __launch_bounds__(256, 4)
void mlp_fused(const float* __restrict__ x,
               const float* __restrict__ W1,
               const float* __restrict__ W2,
               const float* __restrict__ W5,
               float* __restrict__ out,
               long long nrows)
{
    // weights staged once per block; rows of sW1 are 80 B (16B-aligned),
    // sW2/sW5 padded to 8 floats/row so float4 reads are aligned
    __shared__ float sW1[NHID][NIN];
    __shared__ float sW2[NHID][8];
    __shared__ float sW5[NHID][8];

    const int t = threadIdx.x;
    if (t < 120) sW1[t / 20][t % 20] = W1[t];
    if (t >= 128 && t < 176) {
        int u = t - 128, r = u >> 3, c = u & 7;
        sW2[r][c] = (c < 6) ? W2[r * 6 + c] : 0.0f;
    }
    if (t >= 192 && t < 240) {
        int u = t - 192, r = u >> 3, c = u & 7;
        sW5[r][c] = (c < 6) ? W5[r * 6 + c] : 0.0f;
    }
    __syncthreads();

    // 2 rows per thread, contiguous: thread covers 160 B of x, 48 B of out
    const long long row0 = ((long long)blockIdx.x * blockDim.x + t) * 2LL;
    if (row0 + 1 >= nrows + 1) return;  // full pairs only (B divisible by 2*256)

    const float4* __restrict__ xp = (const float4*)(x + row0 * NIN);
    float4 xv[10];
#pragma unroll
    for (int i = 0; i < 10; ++i) xv[i] = xp[i];

    // layer 1: [20] -> [6], sigmoid
    float h0[NHID], h1[NHID];
#pragma unroll
    for (int j = 0; j < NHID; ++j) {
        const float4* wp = (const float4*)(&sW1[j][0]);
        float a0 = 0.0f, a1 = 0.0f;
#pragma unroll
        for (int k = 0; k < 5; ++k) {
            float4 w  = wp[k];
            float4 u0 = xv[k];
            float4 u1 = xv[5 + k];
            a0 = fmaf(u0.x, w.x, a0); a0 = fmaf(u0.y, w.y, a0);
            a0 = fmaf(u0.z, w.z, a0); a0 = fmaf(u0.w, w.w, a0);
            a1 = fmaf(u1.x, w.x, a1); a1 = fmaf(u1.y, w.y, a1);
            a1 = fmaf(u1.z, w.z, a1); a1 = fmaf(u1.w, w.w, a1);
        }
        h0[j] = fsig(a0);
        h1[j] = fsig(a1);
    }

    // layer 2: [6] -> [6], sigmoid
    float g0[NHID], g1[NHID];
#pragma unroll
    for (int j = 0; j < NHID; ++j) {
        float a0 = 0.0f, a1 = 0.0f;
#pragma unroll
        for (int k = 0; k < NHID; ++k) {
            float w = sW2[j][k];
            a0 = fmaf(h0[k], w, a0);
            a1 = fmaf(h1[k], w, a1);
        }
        g0[j] = fsig(a0);
        g1[j] = fsig(a1);
    }

    // layer 3: [6] -> [6], no activation
    float o0[NOUT], o1[NOUT];
#pragma unroll
    for (int j = 0; j < NOUT; ++j) {
        float a0 = 0.0f, a1 = 0.0f;
#pragma unroll
        for (int k = 0; k < NHID; ++k) {
            float w = sW5[j][k];
            a0 = fmaf(g0[k], w, a0);
            a1 = fmaf(g1[k], w, a1);
        }
        o0[j] = a0;
        o1[j] = a1;
    }

    // 12 contiguous floats per thread -> 3x float4, 16B-aligned (row0*24 B, row0 even)
    float4* __restrict__ op = (float4*)(out + row0 * NOUT);
    op[0] = make_float4(o0[0], o0[1], o0[2], o0[3]);
    op[1] = make_float4(o0[4], o0[5], o1[0], o1[1]);
    op[2] = make_float4(o1[2], o1[3], o1[4], o1[5]);
}

extern "C" void kernel_launch(void* const* d_in, const int* in_sizes, int n_in,
                              void* d_out, int out_size, void* d_ws, size_t ws_size,
                              hipStream_t stream) {
    const float* x  = (const float*)d_in[0];
    const float* W1 = (const float*)d_in[1];
    const float* W2 = (const float*)d_in[2];
    const float* W5 = (const float*)d_in[3];
    float* out = (float*)d_out;

    const long long nrows = (long long)in_sizes[0] / NIN;   // 4194304
    const int block = 256;
    const long long rows_per_block = (long long)block * 2;
    const int grid = (int)((nrows + rows_per_block - 1) / rows_per_block);  // 8192
    mlp_fused<<<grid, block, 0, stream>>>(x, W1, W2, W5, out, nrows);
}